// Round 1
// baseline (811.061 us; speedup 1.0000x reference)
//
#include <hip/hip_runtime.h>

#define NN 100000
#define NE 600000
#define NR 6
#define NB 6

// ---------- helpers ----------
__host__ __device__ constexpr int ceil4(int x) { return (x + 3) & ~3; }
__host__ __device__ constexpr int wstride(int in4) {
  return ((in4 + 4) % 32) ? (in4 + 4) : (in4 + 8);
}

// meta layout (ints): [0..5]=cnt, [6..12]=off, [13..19]=tiles_before, [20..25]=cur
// ---------- sort-by-relation kernels ----------
__global__ void hist_kernel(const int* __restrict__ et, int* __restrict__ meta) {
  __shared__ int l[NR];
  if (threadIdx.x < NR) l[threadIdx.x] = 0;
  __syncthreads();
  int e = blockIdx.x * 256 + threadIdx.x;
  if (e < NE) atomicAdd(&l[et[e]], 1);
  __syncthreads();
  if (threadIdx.x < NR) atomicAdd(&meta[threadIdx.x], l[threadIdx.x]);
}

__global__ void scan_meta(int* meta) {
  if (threadIdx.x == 0 && blockIdx.x == 0) {
    int* cnt = meta;
    int* off = meta + 6;
    int* tb  = meta + 13;
    off[0] = 0; tb[0] = 0;
    for (int r = 0; r < NR; ++r) {
      off[r + 1] = off[r] + cnt[r];
      tb[r + 1]  = tb[r] + (cnt[r] + 63) / 64;
    }
  }
}

__global__ void scatter_kernel(const int* __restrict__ et, const int* __restrict__ src,
                               const int* __restrict__ dst, int* __restrict__ meta,
                               int* __restrict__ ssrc, int* __restrict__ sdst) {
  __shared__ int lcnt[NR], lbase[NR];
  if (threadIdx.x < NR) lcnt[threadIdx.x] = 0;
  __syncthreads();
  int e = blockIdx.x * 256 + threadIdx.x;
  int r = 0, rank = 0;
  if (e < NE) { r = et[e]; rank = atomicAdd(&lcnt[r], 1); }
  __syncthreads();
  if (threadIdx.x < NR)
    lbase[threadIdx.x] = lcnt[threadIdx.x] ? atomicAdd(&meta[20 + threadIdx.x], lcnt[threadIdx.x]) : 0;
  __syncthreads();
  if (e < NE) {
    int p = meta[6 + r] + lbase[r] + rank;
    ssrc[p] = src[e];
    sdst[p] = dst[e];
  }
}

// ---------- weight composition (writes transposed, padded, zero-filled) ----------
template <int IN, int OUT>
__global__ void compose_w(const float* __restrict__ V, const float* __restrict__ C,
                          float* __restrict__ WT) {
  constexpr int IN4 = ceil4(IN), WS = wstride(IN4);
  int idx = blockIdx.x * 256 + threadIdx.x;
  if (idx >= NR * OUT * WS) return;
  int r = idx / (OUT * WS);
  int rem = idx % (OUT * WS);
  int o = rem / WS, i = rem % WS;
  float v = 0.f;
  if (i < IN) {
#pragma unroll
    for (int b = 0; b < NB; ++b) v += C[r * NB + b] * V[(b * IN + i) * OUT + o];
  }
  WT[idx] = v;
}

template <int IN, int OUT>
__global__ void transpose_s(const float* __restrict__ S, float* __restrict__ ST) {
  constexpr int IN4 = ceil4(IN), WS = wstride(IN4);
  int idx = blockIdx.x * 256 + threadIdx.x;
  if (idx >= OUT * WS) return;
  int o = idx / WS, i = idx % WS;
  ST[idx] = (i < IN) ? S[i * OUT + o] : 0.f;
}

// ---------- main GEMM (self or edge-bucket) ----------
// EDGE: rows = 64 edges of one relation bucket; A row j = h[sorted_src[..]];
//       epilogue atomicAdd into G[sorted_dst[..]].
// SELF: rows = 64 consecutive nodes; epilogue G[row] = acc + bias.
template <int IN, int OUT, bool RELU_IN, bool EDGE>
__global__ __launch_bounds__(256) void rgcn_gemm(
    const float* __restrict__ h, const float* __restrict__ WT_all,
    const float* __restrict__ bias, float* __restrict__ G,
    const int* __restrict__ ssrc, const int* __restrict__ sdst,
    const int* __restrict__ meta) {
  constexpr int IN4 = ceil4(IN), WS = wstride(IN4);
  constexpr int CGW = OUT / 4;   // lanes per col group (cols strided by CGW)
  constexpr int NRG = 256 / CGW; // row groups
  constexpr int RPT = 64 / NRG;  // rows per thread

  __shared__ float Alds[64 * IN4];
  __shared__ float Wlds[OUT * WS];
  __shared__ int src_lds[64];
  __shared__ int dst_lds[64];

  const int tid = threadIdx.x;
  int row0 = 0, valid_rows = 0;
  const float* WT;

  if constexpr (EDGE) {
    const int* tb = meta + 13;
    int b = blockIdx.x;
    if (b >= tb[6]) return;
    int r = 0;
    while (b >= tb[r + 1]) ++r;
    const int* off = meta + 6;
    int start = off[r] + (b - tb[r]) * 64;
    valid_rows = min(64, off[r + 1] - start);
    row0 = start;
    WT = WT_all + r * (OUT * WS);
    if (tid < 64) {
      int ok = tid < valid_rows;
      src_lds[tid] = ok ? ssrc[start + tid] : -1;
      dst_lds[tid] = ok ? sdst[start + tid] : -1;
    }
    __syncthreads();
  } else {
    row0 = blockIdx.x * 64;
    valid_rows = min(64, NN - row0);
    WT = WT_all;
  }

  // stage W (contiguous, coalesced)
  for (int idx = tid; idx < OUT * WS / 4; idx += 256)
    ((float4*)Wlds)[idx] = ((const float4*)WT)[idx];

  // stage A (gathered rows, relu-on-load, zero padding)
  if constexpr (IN % 4 == 0) {
    constexpr int KV = IN4 / 4;
    for (int idx = tid; idx < 64 * KV; idx += 256) {
      int j = idx / KV, k4 = idx % KV;
      float4 v = make_float4(0.f, 0.f, 0.f, 0.f);
      int s;
      if constexpr (EDGE) s = src_lds[j];
      else s = (j < valid_rows) ? (row0 + j) : -1;
      if (s >= 0) {
        v = *(const float4*)&h[(size_t)s * IN + k4 * 4];
        if (RELU_IN) {
          v.x = fmaxf(v.x, 0.f); v.y = fmaxf(v.y, 0.f);
          v.z = fmaxf(v.z, 0.f); v.w = fmaxf(v.w, 0.f);
        }
      }
      *(float4*)&Alds[j * IN4 + k4 * 4] = v;
    }
  } else {
    for (int idx = tid; idx < 64 * IN4; idx += 256) {
      int j = idx / IN4, k = idx % IN4;
      float v = 0.f;
      int s;
      if constexpr (EDGE) s = src_lds[j];
      else s = (j < valid_rows) ? (row0 + j) : -1;
      if (s >= 0 && k < IN) {
        v = h[(size_t)s * IN + k];
        if (RELU_IN) v = fmaxf(v, 0.f);
      }
      Alds[j * IN4 + k] = v;
    }
  }
  __syncthreads();

  const int colbase = tid % CGW;
  const int rowgrp = tid / CGW;
  float acc[RPT][4];
#pragma unroll
  for (int rr = 0; rr < RPT; ++rr)
#pragma unroll
    for (int j = 0; j < 4; ++j) acc[rr][j] = 0.f;

#pragma unroll 2
  for (int k4 = 0; k4 < IN4 / 4; ++k4) {
    float4 w[4];
#pragma unroll
    for (int j = 0; j < 4; ++j)
      w[j] = *(const float4*)&Wlds[(colbase + j * CGW) * WS + k4 * 4];
#pragma unroll
    for (int rr = 0; rr < RPT; ++rr) {
      float4 a = *(const float4*)&Alds[(rowgrp * RPT + rr) * IN4 + k4 * 4];
#pragma unroll
      for (int j = 0; j < 4; ++j)
        acc[rr][j] += a.x * w[j].x + a.y * w[j].y + a.z * w[j].z + a.w * w[j].w;
    }
  }

  if constexpr (EDGE) {
#pragma unroll
    for (int rr = 0; rr < RPT; ++rr) {
      int d = dst_lds[rowgrp * RPT + rr];
      if (d >= 0) {
#pragma unroll
        for (int j = 0; j < 4; ++j)
          atomicAdd(&G[(size_t)d * OUT + colbase + j * CGW], acc[rr][j]);
      }
    }
  } else {
#pragma unroll
    for (int rr = 0; rr < RPT; ++rr) {
      int row = row0 + rowgrp * RPT + rr;
      if (row < NN) {
#pragma unroll
        for (int j = 0; j < 4; ++j) {
          int c = colbase + j * CGW;
          G[(size_t)row * OUT + c] = acc[rr][j] + bias[c];
        }
      }
    }
  }
}

__global__ void relu_kernel(float* __restrict__ x, int n) {
  int i = blockIdx.x * 256 + threadIdx.x;
  if (i < n) x[i] = fmaxf(x[i], 0.f);
}

// ---------- host ----------
extern "C" void kernel_launch(void* const* d_in, const int* in_sizes, int n_in,
                              void* d_out, int out_size, void* d_ws, size_t ws_size,
                              hipStream_t stream) {
  const float* nf = (const float*)d_in[0];
  const int* src  = (const int*)d_in[1];
  const int* dst  = (const int*)d_in[2];
  const int* et   = (const int*)d_in[3];
  const float* V1 = (const float*)d_in[4];
  const float* C1 = (const float*)d_in[5];
  const float* S1 = (const float*)d_in[6];
  const float* b1 = (const float*)d_in[7];
  const float* V2 = (const float*)d_in[8];
  const float* C2 = (const float*)d_in[9];
  const float* S2 = (const float*)d_in[10];
  const float* b2 = (const float*)d_in[11];
  const float* V3 = (const float*)d_in[12];
  const float* C3 = (const float*)d_in[13];
  const float* S3 = (const float*)d_in[14];
  const float* b3 = (const float*)d_in[15];
  float* out = (float*)d_out;

  constexpr int WS1 = wstride(ceil4(26));   // 36
  constexpr int WS2 = wstride(ceil4(64));   // 68
  constexpr int WS3 = wstride(ceil4(128));  // 132

  char* p = (char*)d_ws;
  int* meta = (int*)p;              p += 256;
  int* ssrc = (int*)p;              p += (size_t)NE * 4;
  int* sdst = (int*)p;              p += (size_t)NE * 4;
  float* WT1 = (float*)p;           p += (size_t)NR * 64 * WS1 * 4;
  float* WT2 = (float*)p;           p += (size_t)NR * 128 * WS2 * 4;
  float* WT3 = (float*)p;           p += (size_t)NR * 32 * WS3 * 4;
  float* ST1 = (float*)p;           p += (size_t)64 * WS1 * 4;
  float* ST2 = (float*)p;           p += (size_t)128 * WS2 * 4;
  float* ST3 = (float*)p;           p += (size_t)32 * WS3 * 4;
  float* G1 = (float*)p;            p += (size_t)NN * 64 * 4;
  float* G2 = (float*)p;            p += (size_t)NN * 128 * 4;

  hipMemsetAsync(meta, 0, 26 * 4, stream);

  const int EB = (NE + 255) / 256;  // 2344
  hist_kernel<<<EB, 256, 0, stream>>>(et, meta);
  scan_meta<<<1, 64, 0, stream>>>(meta);
  scatter_kernel<<<EB, 256, 0, stream>>>(et, src, dst, meta, ssrc, sdst);

  compose_w<26, 64><<<(NR * 64 * WS1 + 255) / 256, 256, 0, stream>>>(V1, C1, WT1);
  compose_w<64, 128><<<(NR * 128 * WS2 + 255) / 256, 256, 0, stream>>>(V2, C2, WT2);
  compose_w<128, 32><<<(NR * 32 * WS3 + 255) / 256, 256, 0, stream>>>(V3, C3, WT3);
  transpose_s<26, 64><<<(64 * WS1 + 255) / 256, 256, 0, stream>>>(S1, ST1);
  transpose_s<64, 128><<<(128 * WS2 + 255) / 256, 256, 0, stream>>>(S2, ST2);
  transpose_s<128, 32><<<(32 * WS3 + 255) / 256, 256, 0, stream>>>(S3, ST3);

  const int NBK = (NN + 63) / 64;        // 1563 self tiles
  const int EGRID = NE / 64 + NR;        // 9381 upper bound on edge tiles

  // Layer 1: 26 -> 64 (input raw)
  rgcn_gemm<26, 64, false, false><<<NBK, 256, 0, stream>>>(nf, ST1, b1, G1, nullptr, nullptr, meta);
  rgcn_gemm<26, 64, false, true><<<EGRID, 256, 0, stream>>>(nf, WT1, nullptr, G1, ssrc, sdst, meta);

  // Layer 2: 64 -> 128 (relu on load of G1)
  rgcn_gemm<64, 128, true, false><<<NBK, 256, 0, stream>>>(G1, ST2, b2, G2, nullptr, nullptr, meta);
  rgcn_gemm<64, 128, true, true><<<EGRID, 256, 0, stream>>>(G1, WT2, nullptr, G2, ssrc, sdst, meta);

  // Layer 3: 128 -> 32 (relu on load of G2), accumulate in d_out
  rgcn_gemm<128, 32, true, false><<<NBK, 256, 0, stream>>>(G2, ST3, b3, out, nullptr, nullptr, meta);
  rgcn_gemm<128, 32, true, true><<<EGRID, 256, 0, stream>>>(G2, WT3, nullptr, out, ssrc, sdst, meta);

  relu_kernel<<<(NN * 32 + 255) / 256, 256, 0, stream>>>(out, NN * 32);

  (void)in_sizes; (void)n_in; (void)out_size; (void)ws_size;
}

// Round 2
// 711.759 us; speedup vs baseline: 1.1395x; 1.1395x over previous
//
#include <hip/hip_runtime.h>

#define NN 100000
#define NE 600000
#define NR 6
#define NB 6
#define NKEY (NN * NR)            // 600000 keys: dst*6 + etype
#define NCHUNK ((NKEY + 1023) / 1024)  // 586

// ---------- helpers ----------
__host__ __device__ constexpr int ceil4(int x) { return (x + 3) & ~3; }
__host__ __device__ constexpr int wstride(int in4) {
  return ((in4 + 4) % 32) ? (in4 + 4) : (in4 + 8);
}

// ---------- input padding: nf [NN][26] -> hp [NN][28] (float4-alignable) ----------
__global__ void pad_feats(const float* __restrict__ nf, float* __restrict__ hp) {
  int idx = blockIdx.x * 256 + threadIdx.x;
  if (idx >= NN * 28) return;
  int n = idx / 28, k = idx - n * 28;
  hp[idx] = (k < 26) ? nf[n * 26 + k] : 0.f;
}

// ---------- CSR build: key = dst*6 + etype ----------
__global__ void hist2(const int* __restrict__ dst, const int* __restrict__ et,
                      int* __restrict__ cnt) {
  int e = blockIdx.x * 256 + threadIdx.x;
  if (e < NE) atomicAdd(&cnt[dst[e] * NR + et[e]], 1);
}

__global__ void scanA(const int* __restrict__ cnt, int* __restrict__ partial) {
  __shared__ int ts[256];
  int t = threadIdx.x;
  int base = blockIdx.x * 1024 + t * 4;
  int s = 0;
#pragma unroll
  for (int i = 0; i < 4; ++i)
    if (base + i < NKEY) s += cnt[base + i];
  ts[t] = s;
  __syncthreads();
  for (int off = 128; off; off >>= 1) {
    if (t < off) ts[t] += ts[t + off];
    __syncthreads();
  }
  if (t == 0) partial[blockIdx.x] = ts[0];
}

__global__ void scanB(int* __restrict__ partial) {
  __shared__ int ts[256];
  int t = threadIdx.x;
  int b = t * 3;
  int v[3], s = 0;
#pragma unroll
  for (int i = 0; i < 3; ++i) {
    v[i] = (b + i < NCHUNK) ? partial[b + i] : 0;
    s += v[i];
  }
  ts[t] = s;
  __syncthreads();
  for (int off = 1; off < 256; off <<= 1) {
    int x = (t >= off) ? ts[t - off] : 0;
    __syncthreads();
    ts[t] += x;
    __syncthreads();
  }
  int run = ts[t] - s;  // exclusive
#pragma unroll
  for (int i = 0; i < 3; ++i) {
    int tmp = v[i];
    if (b + i < NCHUNK) partial[b + i] = run;
    run += tmp;
  }
}

// cnt -> (indptr, cur); cur aliases cnt is fine since each thread reads before writing
__global__ void scanC(int* __restrict__ cnt, const int* __restrict__ partial,
                      int* __restrict__ indptr, int* __restrict__ cur) {
  __shared__ int ts[256];
  int t = threadIdx.x;
  int base = blockIdx.x * 1024 + t * 4;
  int v[4], s = 0;
#pragma unroll
  for (int i = 0; i < 4; ++i) {
    v[i] = (base + i < NKEY) ? cnt[base + i] : 0;
    s += v[i];
  }
  ts[t] = s;
  __syncthreads();
  for (int off = 1; off < 256; off <<= 1) {
    int x = (t >= off) ? ts[t - off] : 0;
    __syncthreads();
    ts[t] += x;
    __syncthreads();
  }
  int run = partial[blockIdx.x] + ts[t] - s;
#pragma unroll
  for (int i = 0; i < 4; ++i) {
    if (base + i < NKEY) {
      indptr[base + i] = run;
      cur[base + i] = run;
      run += v[i];
    }
  }
  if (blockIdx.x == 0 && t == 0) indptr[NKEY] = NE;
}

__global__ void scatter2(const int* __restrict__ et, const int* __restrict__ src,
                         const int* __restrict__ dst, int* __restrict__ cur,
                         int* __restrict__ sidx) {
  int e = blockIdx.x * 256 + threadIdx.x;
  if (e < NE) {
    int key = dst[e] * NR + et[e];
    int pos = atomicAdd(&cur[key], 1);
    sidx[pos] = src[e];
  }
}

// ---------- weight composition (transposed, padded, zero-filled) ----------
template <int IN, int OUT>
__global__ void compose_w(const float* __restrict__ V, const float* __restrict__ C,
                          float* __restrict__ WT) {
  constexpr int IN4 = ceil4(IN), WS = wstride(IN4);
  int idx = blockIdx.x * 256 + threadIdx.x;
  if (idx >= NR * OUT * WS) return;
  int r = idx / (OUT * WS);
  int rem = idx % (OUT * WS);
  int o = rem / WS, i = rem % WS;
  float v = 0.f;
  if (i < IN) {
#pragma unroll
    for (int b = 0; b < NB; ++b) v += C[r * NB + b] * V[(b * IN + i) * OUT + o];
  }
  WT[idx] = v;
}

template <int IN, int OUT>
__global__ void transpose_s(const float* __restrict__ S, float* __restrict__ ST) {
  constexpr int IN4 = ceil4(IN), WS = wstride(IN4);
  int idx = blockIdx.x * 256 + threadIdx.x;
  if (idx >= OUT * WS) return;
  int o = idx / WS, i = idx % WS;
  ST[idx] = (i < IN) ? S[i * OUT + o] : 0.f;
}

// ---------- fused layer: aggregate-then-transform, no atomics ----------
// Block = 64 dst rows. For rel in 0..NR: build A-tile = per-row segmented sum of
// h[src] (rel==NR -> self rows), stage W[rel] (rel==NR -> ST), FMA-accumulate.
// Epilogue: G[row][col] = relu(acc + bias[col]).
template <int IN4, int OUT>
__global__ __launch_bounds__(256) void rgcn_layer(
    const float* __restrict__ h,     // [NN][IN4], padded, already relu'd
    const float* __restrict__ WT,    // [NR][OUT][WS]
    const float* __restrict__ ST,    // [OUT][WS]
    const float* __restrict__ bias,  // [OUT]
    const int* __restrict__ indptr,  // [NKEY+1]
    const int* __restrict__ sidx,    // [NE]
    float* __restrict__ G) {         // [NN][OUT]
  constexpr int WS = wstride(IN4);
  constexpr int WSV = WS / 4;        // odd (9 / 17 / 33) -> bank-spread
  constexpr int KV = IN4 / 4;
  constexpr int CGW = OUT / 4;
  constexpr int NRG = 256 / CGW;
  constexpr int RPT = 64 / NRG;

  __shared__ float4 A4[64 * WSV];
  __shared__ float4 W4[OUT * WSV];
  __shared__ int seg[64 * NR + 1];

  const int tid = threadIdx.x;
  const int row0 = blockIdx.x * 64;
  const float4* __restrict__ h4 = (const float4*)h;

  // stage segment offsets for this tile (contiguous in indptr)
  for (int i = tid; i < 64 * NR + 1; i += 256) {
    int k = row0 * NR + i;
    seg[i] = (k <= NKEY) ? indptr[k] : NE;
  }

  const int colbase = tid % CGW;
  const int rowgrp = tid / CGW;
  float acc[RPT][4];
#pragma unroll
  for (int rr = 0; rr < RPT; ++rr)
#pragma unroll
    for (int j = 0; j < 4; ++j) acc[rr][j] = 0.f;

  for (int rel = 0; rel <= NR; ++rel) {
    __syncthreads();  // protects A4/W4 reuse (and seg on first iter)

    // stage W (coalesced)
    const float4* wsrc = (rel < NR) ? ((const float4*)WT) + rel * OUT * WSV
                                    : (const float4*)ST;
    for (int idx = tid; idx < OUT * WSV; idx += 256) W4[idx] = wsrc[idx];

    // build A tile: row j, chunk c
    for (int idx = tid; idx < 64 * KV; idx += 256) {
      int j = idx / KV, c = idx - j * KV;
      float4 v = make_float4(0.f, 0.f, 0.f, 0.f);
      int row = row0 + j;
      if (row < NN) {
        if (rel == NR) {
          v = h4[(size_t)row * KV + c];
        } else {
          int beg = seg[j * NR + rel], end = seg[j * NR + rel + 1];
          for (int e = beg; e < end; ++e) {
            float4 t = h4[(size_t)sidx[e] * KV + c];
            v.x += t.x; v.y += t.y; v.z += t.z; v.w += t.w;
          }
        }
      }
      A4[j * WSV + c] = v;
    }
    __syncthreads();

    // FMA accumulate (acc persists across rel)
#pragma unroll 2
    for (int k4 = 0; k4 < KV; ++k4) {
      float4 w[4];
#pragma unroll
      for (int j = 0; j < 4; ++j) w[j] = W4[(colbase + j * CGW) * WSV + k4];
#pragma unroll
      for (int rr = 0; rr < RPT; ++rr) {
        float4 a = A4[(rowgrp * RPT + rr) * WSV + k4];
#pragma unroll
        for (int j = 0; j < 4; ++j)
          acc[rr][j] += a.x * w[j].x + a.y * w[j].y + a.z * w[j].z + a.w * w[j].w;
      }
    }
  }

  // epilogue: bias + relu, single write
#pragma unroll
  for (int rr = 0; rr < RPT; ++rr) {
    int row = row0 + rowgrp * RPT + rr;
    if (row < NN) {
#pragma unroll
      for (int j = 0; j < 4; ++j) {
        int c = colbase + j * CGW;
        G[(size_t)row * OUT + c] = fmaxf(acc[rr][j] + bias[c], 0.f);
      }
    }
  }
}

// ---------- host ----------
static inline char* align_up(char* p, size_t a) {
  return (char*)(((size_t)p + a - 1) & ~(a - 1));
}

extern "C" void kernel_launch(void* const* d_in, const int* in_sizes, int n_in,
                              void* d_out, int out_size, void* d_ws, size_t ws_size,
                              hipStream_t stream) {
  const float* nf = (const float*)d_in[0];
  const int* src  = (const int*)d_in[1];
  const int* dst  = (const int*)d_in[2];
  const int* et   = (const int*)d_in[3];
  const float* V1 = (const float*)d_in[4];
  const float* C1 = (const float*)d_in[5];
  const float* S1 = (const float*)d_in[6];
  const float* b1 = (const float*)d_in[7];
  const float* V2 = (const float*)d_in[8];
  const float* C2 = (const float*)d_in[9];
  const float* S2 = (const float*)d_in[10];
  const float* b2 = (const float*)d_in[11];
  const float* V3 = (const float*)d_in[12];
  const float* C3 = (const float*)d_in[13];
  const float* S3 = (const float*)d_in[14];
  const float* b3 = (const float*)d_in[15];
  float* out = (float*)d_out;

  constexpr int WS1 = wstride(28);   // 36
  constexpr int WS2 = wstride(64);   // 68
  constexpr int WS3 = wstride(132 - 4);  // wstride(128) = 132

  char* p = (char*)d_ws;
  int* cnt = (int*)p;      p = align_up(p + (size_t)NKEY * 4, 256);         // doubles as cur
  int* indptr = (int*)p;   p = align_up(p + (size_t)(NKEY + 1) * 4, 256);
  int* partial = (int*)p;  p = align_up(p + (size_t)NCHUNK * 4, 256);
  int* sidx = (int*)p;     p = align_up(p + (size_t)NE * 4, 256);
  float* hp = (float*)p;   p = align_up(p + (size_t)NN * 28 * 4, 256);
  float* WT1 = (float*)p;  p = align_up(p + (size_t)NR * 64 * WS1 * 4, 256);
  float* WT2 = (float*)p;  p = align_up(p + (size_t)NR * 128 * WS2 * 4, 256);
  float* WT3 = (float*)p;  p = align_up(p + (size_t)NR * 32 * WS3 * 4, 256);
  float* ST1 = (float*)p;  p = align_up(p + (size_t)64 * WS1 * 4, 256);
  float* ST2 = (float*)p;  p = align_up(p + (size_t)128 * WS2 * 4, 256);
  float* ST3 = (float*)p;  p = align_up(p + (size_t)32 * WS3 * 4, 256);
  float* G1 = (float*)p;   p = align_up(p + (size_t)NN * 64 * 4, 256);
  float* G2 = (float*)p;   p = align_up(p + (size_t)NN * 128 * 4, 256);

  hipMemsetAsync(cnt, 0, (size_t)NKEY * 4, stream);

  const int EB = (NE + 255) / 256;  // 2344
  pad_feats<<<(NN * 28 + 255) / 256, 256, 0, stream>>>(nf, hp);
  hist2<<<EB, 256, 0, stream>>>(dst, et, cnt);
  scanA<<<NCHUNK, 256, 0, stream>>>(cnt, partial);
  scanB<<<1, 256, 0, stream>>>(partial);
  scanC<<<NCHUNK, 256, 0, stream>>>(cnt, partial, indptr, cnt);
  scatter2<<<EB, 256, 0, stream>>>(et, src, dst, cnt, sidx);

  compose_w<26, 64><<<(NR * 64 * WS1 + 255) / 256, 256, 0, stream>>>(V1, C1, WT1);
  compose_w<64, 128><<<(NR * 128 * WS2 + 255) / 256, 256, 0, stream>>>(V2, C2, WT2);
  compose_w<128, 32><<<(NR * 32 * WS3 + 255) / 256, 256, 0, stream>>>(V3, C3, WT3);
  transpose_s<26, 64><<<(64 * WS1 + 255) / 256, 256, 0, stream>>>(S1, ST1);
  transpose_s<64, 128><<<(128 * WS2 + 255) / 256, 256, 0, stream>>>(S2, ST2);
  transpose_s<128, 32><<<(32 * WS3 + 255) / 256, 256, 0, stream>>>(S3, ST3);

  const int NBK = (NN + 63) / 64;  // 1563
  rgcn_layer<28, 64><<<NBK, 256, 0, stream>>>(hp, WT1, ST1, b1, indptr, sidx, G1);
  rgcn_layer<64, 128><<<NBK, 256, 0, stream>>>(G1, WT2, ST2, b2, indptr, sidx, G2);
  rgcn_layer<128, 32><<<NBK, 256, 0, stream>>>(G2, WT3, ST3, b3, indptr, sidx, out);

  (void)in_sizes; (void)n_in; (void)out_size; (void)ws_size;
}